// Round 4
// baseline (233.595 us; speedup 1.0000x reference)
//
#include <hip/hip_runtime.h>
#include <stdint.h>

#define THRESH 6.0f
#define MAXOUT 128
#define NOC 32      // outlier-column capacity in the MFMA extension
#define KEXT 128    // extension K (bf16): x=[hi|lo|hi|0], w=[hi|hi|lo|0]

typedef float  floatx4 __attribute__((ext_vector_type(4)));
typedef short  shortx8 __attribute__((ext_vector_type(8)));
typedef int    intx4   __attribute__((ext_vector_type(4)));
typedef unsigned short ushort_t;

__device__ __forceinline__ ushort_t f2bf(float x) {
    union { float f; uint32_t u; } v; v.f = x;
    return (ushort_t)(v.u >> 16);   // truncation; hi/lo split absorbs the error
}
__device__ __forceinline__ float bf2f(ushort_t b) {
    union { float f; uint32_t u; } v; v.u = ((uint32_t)b) << 16;
    return v.f;
}

// ---------------- K1: column absmax of x (float4; no memset needed:
// ws poison 0xAAAAAAAA is negative as int, values are >= 0) ------------------
__global__ __launch_bounds__(256) void colmax_kernel(const float* __restrict__ x,
                                                     float* __restrict__ colmax,
                                                     int IN, int rows_per_block) {
    int n4 = IN >> 2;
    int c4 = blockIdx.x * 256 + threadIdx.x;
    if (c4 >= n4) return;
    int r0 = blockIdx.y * rows_per_block;
    const floatx4* x4 = (const floatx4*)x;
    floatx4 m = {0.f, 0.f, 0.f, 0.f};
    for (int r = r0; r < r0 + rows_per_block; ++r) {
        floatx4 v = x4[(size_t)r * n4 + c4];
        #pragma unroll
        for (int i = 0; i < 4; ++i) m[i] = fmaxf(m[i], fabsf(v[i]));
    }
    #pragma unroll
    for (int i = 0; i < 4; ++i)
        atomicMax((int*)&colmax[c4 * 4 + i], __float_as_int(m[i]));  // values >= 0
}

// ---------------- K2: ordered compaction of outlier column indices ----------
__global__ void compact_kernel(const float* __restrict__ colmax, int* __restrict__ nout,
                               int* __restrict__ oidx, int IN) {
    __shared__ int base;
    __shared__ int wsum[4];
    int tid = threadIdx.x, lane = tid & 63, w = tid >> 6;
    if (tid == 0) base = 0;
    __syncthreads();
    for (int c0 = 0; c0 < IN; c0 += 256) {
        int c = c0 + tid;
        bool p = (c < IN) && (colmax[c] > THRESH);
        unsigned long long mask = __ballot(p);
        int prefix = __popcll(mask & ((1ull << lane) - 1ull));
        if (lane == 0) wsum[w] = __popcll(mask);
        __syncthreads();
        int wbase = base;
        for (int i = 0; i < w; ++i) wbase += wsum[i];
        if (p) {
            int pos = wbase + prefix;
            if (pos < MAXOUT) oidx[pos] = c;
        }
        __syncthreads();
        if (tid == 0) base += wsum[0] + wsum[1] + wsum[2] + wsum[3];
        __syncthreads();
    }
    if (tid == 0) *nout = (base < MAXOUT) ? base : MAXOUT;
}

// ---------------- K3: wave-per-row quantization (registers, no LDS) ---------
// Global wave id < T: token row of x (colmax-masked absmax); else weight row.
template<int NITER>   // NITER = IN/256; row held in NITER float4 regs per lane
__global__ __launch_bounds__(256) void quant_kernel(
    const float* __restrict__ x, const float* __restrict__ w,
    const float* __restrict__ colmax,
    const int* __restrict__ oidx, const int* __restrict__ nout,
    int8_t* __restrict__ xq, int8_t* __restrict__ wq,
    float* __restrict__ xscale, float* __restrict__ wscale,
    ushort_t* __restrict__ xoc2, ushort_t* __restrict__ woc2,
    int IN, int T, int TOTAL) {
    int wid = blockIdx.x * 4 + (threadIdx.x >> 6);
    if (wid >= TOTAL) return;
    int lane = threadIdx.x & 63;
    bool isW = wid >= T;
    int r = isW ? wid - T : wid;
    const float* src = (isW ? w : x) + (size_t)r * IN;
    const floatx4* src4 = (const floatx4*)src;
    const floatx4* cm4 = (const floatx4*)colmax;

    floatx4 rowv[NITER];
    float m = 0.f;
    #pragma unroll
    for (int i = 0; i < NITER; ++i) {
        floatx4 v = src4[i * 64 + lane];
        rowv[i] = v;
        if (isW) {
            #pragma unroll
            for (int k = 0; k < 4; ++k) m = fmaxf(m, fabsf(v[k]));
        } else {
            floatx4 cm = cm4[i * 64 + lane];
            #pragma unroll
            for (int k = 0; k < 4; ++k)
                if (!(cm[k] > THRESH)) m = fmaxf(m, fabsf(v[k]));
        }
    }
    #pragma unroll
    for (int off = 32; off; off >>= 1) m = fmaxf(m, __shfl_down(m, off));
    m = __shfl(m, 0);

    float absmax = fmaxf(m, 1e-6f);
    float inv = 127.0f / absmax, scale = absmax / 127.0f;

    uint32_t* dst = (uint32_t*)((isW ? wq : xq) + (size_t)r * IN);
    #pragma unroll
    for (int i = 0; i < NITER; ++i) {
        floatx4 v = rowv[i];
        if (!isW) {
            floatx4 cm = cm4[i * 64 + lane];   // L1-hot reload
            #pragma unroll
            for (int k = 0; k < 4; ++k) if (cm[k] > THRESH) v[k] = 0.f;
        }
        uint32_t pk = 0;
        #pragma unroll
        for (int k = 0; k < 4; ++k) {
            int q = (int)rintf(fminf(fmaxf(v[k] * inv, -127.f), 127.f));
            pk |= ((uint32_t)(uint8_t)(int8_t)q) << (8 * k);
        }
        dst[i * 64 + lane] = pk;
    }
    if (lane == 0) (isW ? wscale : xscale)[r] = scale;

    // extension row [KEXT=128 bf16]: lane computes entries {2*lane, 2*lane+1}
    int no = *nout; if (no > NOC) no = NOC;
    uint32_t pk = 0;
    #pragma unroll
    for (int s = 0; s < 2; ++s) {
        int e = 2 * lane + s;
        int j = e & 31, part = e >> 5;
        ushort_t val = 0;
        if (j < no && part < 3) {
            float v = src[oidx[j]];            // L1/L2-hot scalar re-read
            if (isW) {
                float q = fminf(fmaxf(rintf(v * inv), -127.f), 127.f);
                v = q * scale;                 // dequantized int8 weight
            }
            ushort_t hi = f2bf(v);
            ushort_t lo = f2bf(v - bf2f(hi));
            if (isW) val = (part == 2) ? lo : hi;        // [hi|hi|lo]
            else     val = (part == 1) ? lo : hi;        // [hi|lo|hi]
        }
        pk |= ((uint32_t)val) << (16 * s);
    }
    ushort_t* ext = (isW ? woc2 : xoc2) + (size_t)r * KEXT;
    ((uint32_t*)ext)[lane] = pk;
}

// Generic fallback (IN not a supported multiple): block-per-row via global re-read
__global__ __launch_bounds__(256) void quant_generic_kernel(
    const float* __restrict__ x, const float* __restrict__ w,
    const float* __restrict__ colmax,
    const int* __restrict__ oidx, const int* __restrict__ nout,
    int8_t* __restrict__ xq, int8_t* __restrict__ wq,
    float* __restrict__ xscale, float* __restrict__ wscale,
    ushort_t* __restrict__ xoc2, ushort_t* __restrict__ woc2,
    int IN, int T) {
    __shared__ float red[4];
    int bid = blockIdx.x, tid = threadIdx.x;
    bool isW = bid >= T;
    int r = isW ? bid - T : bid;
    const float* src = (isW ? w : x) + (size_t)r * IN;
    float m = 0.f;
    for (int c = tid; c < IN; c += 256) {
        float v = src[c];
        if (isW || !(colmax[c] > THRESH)) m = fmaxf(m, fabsf(v));
    }
    #pragma unroll
    for (int off = 32; off; off >>= 1) m = fmaxf(m, __shfl_down(m, off));
    if ((tid & 63) == 0) red[tid >> 6] = m;
    __syncthreads();
    m = fmaxf(fmaxf(red[0], red[1]), fmaxf(red[2], red[3]));
    float absmax = fmaxf(m, 1e-6f);
    float inv = 127.0f / absmax, scale = absmax / 127.0f;
    int8_t* dst = (isW ? wq : xq) + (size_t)r * IN;
    for (int c = tid; c < IN; c += 256) {
        float v = src[c];
        if (!isW && colmax[c] > THRESH) v = 0.f;
        dst[c] = (int8_t)(int)rintf(fminf(fmaxf(v * inv, -127.f), 127.f));
    }
    if (tid == 0) (isW ? wscale : xscale)[r] = scale;
    int no = *nout; if (no > NOC) no = NOC;
    ushort_t* ext = (isW ? woc2 : xoc2) + (size_t)r * KEXT;
    if (tid < KEXT) {
        int j = tid & 31, part = tid >> 5;
        ushort_t val = 0;
        if (j < no && part < 3) {
            float v = src[oidx[j]];
            if (isW) { float q = fminf(fmaxf(rintf(v * inv), -127.f), 127.f); v = q * scale; }
            ushort_t hi = f2bf(v);
            ushort_t lo = f2bf(v - bf2f(hi));
            if (isW) val = (part == 2) ? lo : hi; else val = (part == 1) ? lo : hi;
        }
        ext[tid] = val;
    }
}

// ---------------- K4: i8 MFMA GEMM + in-place scale + bf16 MFMA extension ---
#define BM 128
#define BN 128
#define BKB 64   // K-tile in BYTES per row: 64 int8 (main) == 32 bf16 (ext)

__device__ __forceinline__ void stage_tiles(const uint8_t* Ab, const uint8_t* Bb,
                                            int strideB, int k0b,
                                            uint8_t* sA, uint8_t* sB, int tid) {
    #pragma unroll
    for (int i = 0; i < 2; ++i) {
        int idx = i * 256 + tid;
        int r = idx >> 2, cb = (idx & 3) * 16;
        __builtin_amdgcn_global_load_lds(
            (const __attribute__((address_space(1))) uint32_t*)(Ab + (size_t)r * strideB + k0b + cb),
            (__attribute__((address_space(3))) uint32_t*)(sA + idx * 16), 16, 0, 0);
        __builtin_amdgcn_global_load_lds(
            (const __attribute__((address_space(1))) uint32_t*)(Bb + (size_t)r * strideB + k0b + cb),
            (__attribute__((address_space(3))) uint32_t*)(sB + idx * 16), 16, 0, 0);
    }
}

union accu_t { intx4 i[4][4]; floatx4 f[4][4]; };

__device__ __forceinline__ void mfma_step_i8(const uint8_t* sA, const uint8_t* sB,
                                             int wm, int wn, int quad, int l16,
                                             accu_t& acc) {
    intx4 af[4], bf[4];
    #pragma unroll
    for (int mt = 0; mt < 4; ++mt)
        af[mt] = *(const intx4*)(sA + (wm + mt * 16 + l16) * BKB + quad * 16);
    #pragma unroll
    for (int nt = 0; nt < 4; ++nt)
        bf[nt] = *(const intx4*)(sB + (wn + nt * 16 + l16) * BKB + quad * 16);
    #pragma unroll
    for (int mt = 0; mt < 4; ++mt)
        #pragma unroll
        for (int nt = 0; nt < 4; ++nt)
            acc.i[mt][nt] = __builtin_amdgcn_mfma_i32_16x16x64_i8(
                af[mt], bf[nt], acc.i[mt][nt], 0, 0, 0);
}

__device__ __forceinline__ void mfma_step_bf16(const uint8_t* sA, const uint8_t* sB,
                                               int wm, int wn, int quad, int l16,
                                               accu_t& acc) {
    shortx8 af[4], bf[4];
    #pragma unroll
    for (int mt = 0; mt < 4; ++mt)
        af[mt] = *(const shortx8*)(sA + (wm + mt * 16 + l16) * BKB + quad * 16);
    #pragma unroll
    for (int nt = 0; nt < 4; ++nt)
        bf[nt] = *(const shortx8*)(sB + (wn + nt * 16 + l16) * BKB + quad * 16);
    #pragma unroll
    for (int mt = 0; mt < 4; ++mt)
        #pragma unroll
        for (int nt = 0; nt < 4; ++nt)
            acc.f[mt][nt] = __builtin_amdgcn_mfma_f32_16x16x32_bf16(
                af[mt], bf[nt], acc.f[mt][nt], 0, 0, 0);
}

__global__ __launch_bounds__(256) void gemm_kernel(
    const int8_t* __restrict__ A,   // xq [T, IN]
    const int8_t* __restrict__ B,   // wq [OUT, IN]
    const float* __restrict__ xscale, const float* __restrict__ wscale,
    const float* __restrict__ bias,
    const ushort_t* __restrict__ xoc2,  // [T, KEXT] bf16
    const ushort_t* __restrict__ woc2,  // [OUT, KEXT] bf16
    float* __restrict__ out, int T, int IN, int OUT)
{
    __shared__ __attribute__((aligned(16))) uint8_t sA[BM * BKB];
    __shared__ __attribute__((aligned(16))) uint8_t sB[BN * BKB];

    int tid = threadIdx.x;
    int m0 = blockIdx.y * BM, n0 = blockIdx.x * BN;
    int lane = tid & 63, w = tid >> 6;
    int wm = (w >> 1) * 64, wn = (w & 1) * 64;
    int quad = lane >> 4, l16 = lane & 15;

    accu_t acc;
    #pragma unroll
    for (int mt = 0; mt < 4; ++mt)
        #pragma unroll
        for (int nt = 0; nt < 4; ++nt)
            acc.i[mt][nt] = (intx4){0, 0, 0, 0};

    const uint8_t* Ab = (const uint8_t*)A + (size_t)m0 * IN;
    const uint8_t* Bb = (const uint8_t*)B + (size_t)n0 * IN;

    int nk = IN / BKB;   // 64 int8 per K-tile
    for (int kt = 0; kt < nk; ++kt) {
        __syncthreads();
        stage_tiles(Ab, Bb, IN, kt * BKB, sA, sB, tid);
        __syncthreads();
        mfma_step_i8(sA, sB, wm, wn, quad, l16, acc);
    }

    // in-place dequant + bias: f = (float)i * xs * ws + bias
    #pragma unroll
    for (int mt = 0; mt < 4; ++mt) {
        floatx4 xs4 = *(const floatx4*)(xscale + m0 + wm + mt * 16 + quad * 4);
        #pragma unroll
        for (int nt = 0; nt < 4; ++nt) {
            int o = n0 + wn + nt * 16 + l16;
            float s = wscale[o], bv = bias[o];
            #pragma unroll
            for (int r = 0; r < 4; ++r)
                acc.f[mt][nt][r] = (float)acc.i[mt][nt][r] * (xs4[r] * s) + bv;
        }
    }

    // outlier fp correction: 2 bf16 MFMA K-tiles (KEXT=128 bf16 = 2 x 64B rows)
    const uint8_t* Ae = (const uint8_t*)xoc2 + (size_t)m0 * (KEXT * 2);
    const uint8_t* Be = (const uint8_t*)woc2 + (size_t)n0 * (KEXT * 2);
    #pragma unroll
    for (int kt = 0; kt < (KEXT * 2) / BKB; ++kt) {
        __syncthreads();
        stage_tiles(Ae, Be, KEXT * 2, kt * BKB, sA, sB, tid);
        __syncthreads();
        mfma_step_bf16(sA, sB, wm, wn, quad, l16, acc);
    }

    // store: D layout col=lane&15, row=quad*4+reg
    #pragma unroll
    for (int mt = 0; mt < 4; ++mt)
        #pragma unroll
        for (int r = 0; r < 4; ++r) {
            int t = m0 + wm + mt * 16 + quad * 4 + r;
            #pragma unroll
            for (int nt = 0; nt < 4; ++nt) {
                int o = n0 + wn + nt * 16 + l16;
                out[(size_t)t * OUT + o] = acc.f[mt][nt][r];
            }
        }
}

extern "C" void kernel_launch(void* const* d_in, const int* in_sizes, int n_in,
                              void* d_out, int out_size, void* d_ws, size_t ws_size,
                              hipStream_t stream) {
    const float* x    = (const float*)d_in[0];
    const float* wgt  = (const float*)d_in[1];
    const float* bias = (const float*)d_in[2];
    float* out = (float*)d_out;

    int OUT = in_sizes[2];
    int IN  = in_sizes[1] / OUT;
    int T   = in_sizes[0] / IN;

    char* p = (char*)d_ws;
    int8_t* xq     = (int8_t*)p;   p += (size_t)T * IN;
    int8_t* wq     = (int8_t*)p;   p += (size_t)OUT * IN;
    ushort_t* xoc2 = (ushort_t*)p; p += (size_t)T * KEXT * 2;
    ushort_t* woc2 = (ushort_t*)p; p += (size_t)OUT * KEXT * 2;
    float* wscale  = (float*)p;    p += (size_t)OUT * 4;
    float* xscale  = (float*)p;    p += (size_t)T * 4;
    float* colmax  = (float*)p;    p += (size_t)IN * 4;
    int*   nout    = (int*)p;      p += 256;
    int*   oidx    = (int*)p;      p += MAXOUT * 4;

    int n4 = IN / 4;
    int gx = (n4 + 255) / 256;
    int grid_y = 128;                      // 1 block/CU at (2,128); 64 rows/block
    colmax_kernel<<<dim3(gx, grid_y), dim3(256), 0, stream>>>(
        x, colmax, IN, T / grid_y);

    compact_kernel<<<dim3(1), dim3(256), 0, stream>>>(colmax, nout, oidx, IN);

    int TOTAL = T + OUT;
    int niter = IN / 256;
    bool ok = (IN % 256 == 0) && (niter == 4 || niter == 8 || niter == 16);
    if (ok) {
        int blocks = (TOTAL + 3) / 4;
        switch (niter) {
        case 4:
            quant_kernel<4><<<dim3(blocks), dim3(256), 0, stream>>>(
                x, wgt, colmax, oidx, nout, xq, wq, xscale, wscale, xoc2, woc2, IN, T, TOTAL);
            break;
        case 8:
            quant_kernel<8><<<dim3(blocks), dim3(256), 0, stream>>>(
                x, wgt, colmax, oidx, nout, xq, wq, xscale, wscale, xoc2, woc2, IN, T, TOTAL);
            break;
        default:
            quant_kernel<16><<<dim3(blocks), dim3(256), 0, stream>>>(
                x, wgt, colmax, oidx, nout, xq, wq, xscale, wscale, xoc2, woc2, IN, T, TOTAL);
            break;
        }
    } else {
        quant_generic_kernel<<<dim3(TOTAL), dim3(256), 0, stream>>>(
            x, wgt, colmax, oidx, nout, xq, wq, xscale, wscale, xoc2, woc2, IN, T);
    }

    gemm_kernel<<<dim3(OUT / BN, T / BM), dim3(256), 0, stream>>>(
        xq, wq, xscale, wscale, bias, xoc2, woc2, out, T, IN, OUT);
}

// Round 5
// 208.616 us; speedup vs baseline: 1.1197x; 1.1197x over previous
//
#include <hip/hip_runtime.h>
#include <stdint.h>

#define THRESH 6.0f
#define MAXOUT 128
#define NOC 32      // outlier-column capacity in the MFMA extension
#define KEXT 128    // ext row (bf16): x=[hi|lo|hi|0], w=[hi|hi|lo|0]; K=96 used
#define NSLAB 256   // column-max partial slabs

typedef float  floatx4  __attribute__((ext_vector_type(4)));
typedef float  floatx16 __attribute__((ext_vector_type(16)));
typedef short  shortx8  __attribute__((ext_vector_type(8)));
typedef int    intx4    __attribute__((ext_vector_type(4)));
typedef int    intx16   __attribute__((ext_vector_type(16)));
typedef unsigned short ushort_t;

__device__ __forceinline__ ushort_t f2bf(float x) {
    union { float f; uint32_t u; } v; v.f = x;
    return (ushort_t)(v.u >> 16);   // truncation; hi/lo split absorbs the error
}
__device__ __forceinline__ float bf2f(ushort_t b) {
    union { float f; uint32_t u; } v; v.u = ((uint32_t)b) << 16;
    return v.f;
}

// ---------------- K1: column absmax partials (atomic-free) ------------------
__global__ __launch_bounds__(256) void colmax_part_kernel(
    const float* __restrict__ x, float* __restrict__ partial,
    int* __restrict__ nout, int n4, int rows_per_slab) {
    if (blockIdx.x == 0 && blockIdx.y == 0 && threadIdx.x == 0) *nout = 0;  // init for reduce
    int c4 = blockIdx.x * 256 + threadIdx.x;
    if (c4 >= n4) return;
    int r0 = blockIdx.y * rows_per_slab;
    const floatx4* x4 = (const floatx4*)x;
    floatx4 m = {0.f, 0.f, 0.f, 0.f};
    #pragma unroll 4
    for (int r = r0; r < r0 + rows_per_slab; ++r) {
        floatx4 v = x4[(size_t)r * n4 + c4];
        #pragma unroll
        for (int i = 0; i < 4; ++i) m[i] = fmaxf(m[i], fabsf(v[i]));
    }
    ((floatx4*)partial)[(size_t)blockIdx.y * n4 + c4] = m;
}

// ---------------- K2: reduce partials -> colmax, + ballot compaction --------
// grid: IN/64 blocks x 256 thr. Wave 0 of each block does the compaction for
// its 64 columns (order across blocks arbitrary -- numerically irrelevant).
__global__ __launch_bounds__(256) void colmax_reduce_kernel(
    const float* __restrict__ partial, float* __restrict__ colmax,
    int* __restrict__ nout, int* __restrict__ oidx, int IN) {
    __shared__ float red[4][64];
    int tid = threadIdx.x, lane = tid & 63, q = tid >> 6;
    int col = blockIdx.x * 64 + lane;
    float m = 0.f;
    for (int s = q; s < NSLAB; s += 4)
        m = fmaxf(m, partial[(size_t)s * IN + col]);
    red[q][lane] = m;
    __syncthreads();
    if (q == 0) {
        m = fmaxf(fmaxf(red[0][lane], red[1][lane]), fmaxf(red[2][lane], red[3][lane]));
        colmax[col] = m;
        bool p = m > THRESH;
        unsigned long long mask = __ballot(p);
        int cnt = __popcll(mask);
        if (cnt > 0) {
            int base = 0;
            if (lane == 0) base = atomicAdd(nout, cnt);
            base = __shfl(base, 0);
            if (p) {
                int pos = base + __popcll(mask & ((1ull << lane) - 1ull));
                if (pos < MAXOUT) oidx[pos] = col;
            }
        }
    }
}

// ---------------- K3: wave-per-row quantization (registers, no LDS) ---------
// Global wave id < T: token row of x (colmax-masked absmax); else weight row.
template<int NITER>   // NITER = IN/256
__global__ __launch_bounds__(256) void quant_kernel(
    const float* __restrict__ x, const float* __restrict__ w,
    const float* __restrict__ colmax,
    const int* __restrict__ oidx, const int* __restrict__ nout,
    int8_t* __restrict__ xq, int8_t* __restrict__ wq,
    float* __restrict__ xscale, float* __restrict__ wscale,
    ushort_t* __restrict__ xoc2, ushort_t* __restrict__ woc2,
    int IN, int T, int TOTAL) {
    int wid = blockIdx.x * 4 + (threadIdx.x >> 6);
    if (wid >= TOTAL) return;
    int lane = threadIdx.x & 63;
    bool isW = wid >= T;
    int r = isW ? wid - T : wid;
    const float* src = (isW ? w : x) + (size_t)r * IN;
    const floatx4* src4 = (const floatx4*)src;
    const floatx4* cm4 = (const floatx4*)colmax;

    floatx4 rowv[NITER];
    float m = 0.f;
    #pragma unroll
    for (int i = 0; i < NITER; ++i) {
        floatx4 v = src4[i * 64 + lane];
        rowv[i] = v;
        if (isW) {
            #pragma unroll
            for (int k = 0; k < 4; ++k) m = fmaxf(m, fabsf(v[k]));
        } else {
            floatx4 cm = cm4[i * 64 + lane];
            #pragma unroll
            for (int k = 0; k < 4; ++k)
                if (!(cm[k] > THRESH)) m = fmaxf(m, fabsf(v[k]));
        }
    }
    #pragma unroll
    for (int off = 32; off; off >>= 1) m = fmaxf(m, __shfl_down(m, off));
    m = __shfl(m, 0);

    float absmax = fmaxf(m, 1e-6f);
    float inv = 127.0f / absmax, scale = absmax / 127.0f;

    uint32_t* dst = (uint32_t*)((isW ? wq : xq) + (size_t)r * IN);
    #pragma unroll
    for (int i = 0; i < NITER; ++i) {
        floatx4 v = rowv[i];
        if (!isW) {
            floatx4 cm = cm4[i * 64 + lane];   // L1-hot reload
            #pragma unroll
            for (int k = 0; k < 4; ++k) if (cm[k] > THRESH) v[k] = 0.f;
        }
        uint32_t pk = 0;
        #pragma unroll
        for (int k = 0; k < 4; ++k) {
            int q = (int)rintf(fminf(fmaxf(v[k] * inv, -127.f), 127.f));
            pk |= ((uint32_t)(uint8_t)(int8_t)q) << (8 * k);
        }
        dst[i * 64 + lane] = pk;
    }
    if (lane == 0) (isW ? wscale : xscale)[r] = scale;

    // extension row [KEXT=128 bf16]: lane computes entries {2*lane, 2*lane+1}
    int no = *nout; if (no > NOC) no = NOC;
    uint32_t pk = 0;
    #pragma unroll
    for (int s = 0; s < 2; ++s) {
        int e = 2 * lane + s;
        int j = e & 31, part = e >> 5;
        ushort_t val = 0;
        if (j < no && part < 3) {
            float v = src[oidx[j]];            // L1/L2-hot scalar re-read
            if (isW) {
                float q = fminf(fmaxf(rintf(v * inv), -127.f), 127.f);
                v = q * scale;                 // dequantized int8 weight
            }
            ushort_t hi = f2bf(v);
            ushort_t lo = f2bf(v - bf2f(hi));
            if (isW) val = (part == 2) ? lo : hi;        // [hi|hi|lo]
            else     val = (part == 1) ? lo : hi;        // [hi|lo|hi]
        }
        pk |= ((uint32_t)val) << (16 * s);
    }
    ushort_t* ext = (isW ? woc2 : xoc2) + (size_t)r * KEXT;
    ((uint32_t*)ext)[lane] = pk;
}

// Generic fallback (IN not a supported multiple)
__global__ __launch_bounds__(256) void quant_generic_kernel(
    const float* __restrict__ x, const float* __restrict__ w,
    const float* __restrict__ colmax,
    const int* __restrict__ oidx, const int* __restrict__ nout,
    int8_t* __restrict__ xq, int8_t* __restrict__ wq,
    float* __restrict__ xscale, float* __restrict__ wscale,
    ushort_t* __restrict__ xoc2, ushort_t* __restrict__ woc2,
    int IN, int T) {
    __shared__ float red[4];
    int bid = blockIdx.x, tid = threadIdx.x;
    bool isW = bid >= T;
    int r = isW ? bid - T : bid;
    const float* src = (isW ? w : x) + (size_t)r * IN;
    float m = 0.f;
    for (int c = tid; c < IN; c += 256) {
        float v = src[c];
        if (isW || !(colmax[c] > THRESH)) m = fmaxf(m, fabsf(v));
    }
    #pragma unroll
    for (int off = 32; off; off >>= 1) m = fmaxf(m, __shfl_down(m, off));
    if ((tid & 63) == 0) red[tid >> 6] = m;
    __syncthreads();
    m = fmaxf(fmaxf(red[0], red[1]), fmaxf(red[2], red[3]));
    float absmax = fmaxf(m, 1e-6f);
    float inv = 127.0f / absmax, scale = absmax / 127.0f;
    int8_t* dst = (isW ? wq : xq) + (size_t)r * IN;
    for (int c = tid; c < IN; c += 256) {
        float v = src[c];
        if (!isW && colmax[c] > THRESH) v = 0.f;
        dst[c] = (int8_t)(int)rintf(fminf(fmaxf(v * inv, -127.f), 127.f));
    }
    if (tid == 0) (isW ? wscale : xscale)[r] = scale;
    int no = *nout; if (no > NOC) no = NOC;
    ushort_t* ext = (isW ? woc2 : xoc2) + (size_t)r * KEXT;
    if (tid < KEXT) {
        int j = tid & 31, part = tid >> 5;
        ushort_t val = 0;
        if (j < no && part < 3) {
            float v = src[oidx[j]];
            if (isW) { float q = fminf(fmaxf(rintf(v * inv), -127.f), 127.f); v = q * scale; }
            ushort_t hi = f2bf(v);
            ushort_t lo = f2bf(v - bf2f(hi));
            if (isW) val = (part == 2) ? lo : hi; else val = (part == 1) ? lo : hi;
        }
        ext[tid] = val;
    }
}

// ---------------- K4: 32x32x32 i8 MFMA GEMM + bf16 32x32x16 ext -------------
#define BM 128
#define BN 128
#define BKB 64   // K-tile bytes/row: 64 int8 (main) == 32 bf16 (ext)

// chunk swizzle: LDS[r][c] holds global[r][c ^ swz(r)] (16B chunks)
__device__ __forceinline__ int swz(int r) { return (r ^ (r >> 2)) & 3; }

__device__ __forceinline__ void stage_tiles(const uint8_t* Ab, const uint8_t* Bb,
                                            int strideB, int k0b,
                                            uint8_t* sA, uint8_t* sB, int tid) {
    #pragma unroll
    for (int i = 0; i < 2; ++i) {
        int idx = i * 256 + tid;
        int r = idx >> 2, c = idx & 3;
        int cb = (c ^ swz(r)) * 16;   // fetch permuted chunk -> linear LDS slot
        __builtin_amdgcn_global_load_lds(
            (const __attribute__((address_space(1))) uint32_t*)(Ab + (size_t)r * strideB + k0b + cb),
            (__attribute__((address_space(3))) uint32_t*)(sA + idx * 16), 16, 0, 0);
        __builtin_amdgcn_global_load_lds(
            (const __attribute__((address_space(1))) uint32_t*)(Bb + (size_t)r * strideB + k0b + cb),
            (__attribute__((address_space(3))) uint32_t*)(sB + idx * 16), 16, 0, 0);
    }
}

__device__ __forceinline__ const uint8_t* frag_addr(const uint8_t* s, int row, int C) {
    return s + row * BKB + ((C ^ swz(row)) * 16);
}

union accu_t { intx16 i[2][2]; floatx16 f[2][2]; };

__global__ __launch_bounds__(256) void gemm_kernel(
    const int8_t* __restrict__ A,   // xq [T, IN]
    const int8_t* __restrict__ B,   // wq [OUT, IN]
    const float* __restrict__ xscale, const float* __restrict__ wscale,
    const float* __restrict__ bias,
    const ushort_t* __restrict__ xoc2,  // [T, KEXT] bf16
    const ushort_t* __restrict__ woc2,  // [OUT, KEXT] bf16
    float* __restrict__ out, int T, int IN, int OUT)
{
    __shared__ __attribute__((aligned(16))) uint8_t sA[BM * BKB];
    __shared__ __attribute__((aligned(16))) uint8_t sB[BN * BKB];

    int tid = threadIdx.x;
    int m0 = blockIdx.y * BM, n0 = blockIdx.x * BN;
    int lane = tid & 63, w = tid >> 6;
    int wm = (w >> 1) * 64, wn = (w & 1) * 64;
    int l31 = lane & 31, half = lane >> 5;

    accu_t acc;
    #pragma unroll
    for (int mt = 0; mt < 2; ++mt)
        #pragma unroll
        for (int nt = 0; nt < 2; ++nt)
            acc.i[mt][nt] = (intx16)(0);

    const uint8_t* Ab = (const uint8_t*)A + (size_t)m0 * IN;
    const uint8_t* Bb = (const uint8_t*)B + (size_t)n0 * IN;

    int nk = IN / BKB;
    for (int kt = 0; kt < nk; ++kt) {
        __syncthreads();
        stage_tiles(Ab, Bb, IN, kt * BKB, sA, sB, tid);
        __syncthreads();
        intx4 af[2][2], bf[2][2];
        #pragma unroll
        for (int mt = 0; mt < 2; ++mt)
            #pragma unroll
            for (int ks = 0; ks < 2; ++ks)
                af[mt][ks] = *(const intx4*)frag_addr(sA, wm + mt * 32 + l31, ks * 2 + half);
        #pragma unroll
        for (int nt = 0; nt < 2; ++nt)
            #pragma unroll
            for (int ks = 0; ks < 2; ++ks)
                bf[nt][ks] = *(const intx4*)frag_addr(sB, wn + nt * 32 + l31, ks * 2 + half);
        #pragma unroll
        for (int mt = 0; mt < 2; ++mt)
            #pragma unroll
            for (int nt = 0; nt < 2; ++nt)
                #pragma unroll
                for (int ks = 0; ks < 2; ++ks)
                    acc.i[mt][nt] = __builtin_amdgcn_mfma_i32_32x32x32_i8(
                        af[mt][ks], bf[nt][ks], acc.i[mt][nt], 0, 0, 0);
    }

    // in-place dequant + bias: f = (float)i * xs * ws + bias
    // C/D 32x32 layout: col=lane&31, row=(reg&3)+8*(reg>>2)+4*(lane>>5)
    #pragma unroll
    for (int mt = 0; mt < 2; ++mt) {
        floatx4 xsg[4];
        #pragma unroll
        for (int g = 0; g < 4; ++g)
            xsg[g] = *(const floatx4*)(xscale + m0 + wm + mt * 32 + g * 8 + half * 4);
        #pragma unroll
        for (int nt = 0; nt < 2; ++nt) {
            int o = n0 + wn + nt * 32 + l31;
            float s = wscale[o], bv = bias[o];
            #pragma unroll
            for (int reg = 0; reg < 16; ++reg)
                acc.f[mt][nt][reg] =
                    (float)acc.i[mt][nt][reg] * (xsg[reg >> 2][reg & 3] * s) + bv;
        }
    }

    // outlier fp correction: 3 bf16 tiles (K=96 useful; 4th tile is zeros)
    const uint8_t* Ae = (const uint8_t*)xoc2 + (size_t)m0 * (KEXT * 2);
    const uint8_t* Be = (const uint8_t*)woc2 + (size_t)n0 * (KEXT * 2);
    #pragma unroll
    for (int kt = 0; kt < 3; ++kt) {
        __syncthreads();
        stage_tiles(Ae, Be, KEXT * 2, kt * BKB, sA, sB, tid);
        __syncthreads();
        shortx8 af[2][2], bf[2][2];
        #pragma unroll
        for (int mt = 0; mt < 2; ++mt)
            #pragma unroll
            for (int ks = 0; ks < 2; ++ks)
                af[mt][ks] = *(const shortx8*)frag_addr(sA, wm + mt * 32 + l31, ks * 2 + half);
        #pragma unroll
        for (int nt = 0; nt < 2; ++nt)
            #pragma unroll
            for (int ks = 0; ks < 2; ++ks)
                bf[nt][ks] = *(const shortx8*)frag_addr(sB, wn + nt * 32 + l31, ks * 2 + half);
        #pragma unroll
        for (int mt = 0; mt < 2; ++mt)
            #pragma unroll
            for (int nt = 0; nt < 2; ++nt)
                #pragma unroll
                for (int ks = 0; ks < 2; ++ks)
                    acc.f[mt][nt] = __builtin_amdgcn_mfma_f32_32x32x16_bf16(
                        af[mt][ks], bf[nt][ks], acc.f[mt][nt], 0, 0, 0);
    }

    // store
    #pragma unroll
    for (int mt = 0; mt < 2; ++mt)
        #pragma unroll
        for (int nt = 0; nt < 2; ++nt) {
            int o = n0 + wn + nt * 32 + l31;
            #pragma unroll
            for (int reg = 0; reg < 16; ++reg) {
                int row = (reg & 3) + 8 * (reg >> 2) + 4 * half;
                int t = m0 + wm + mt * 32 + row;
                out[(size_t)t * OUT + o] = acc.f[mt][nt][reg];
            }
        }
}

extern "C" void kernel_launch(void* const* d_in, const int* in_sizes, int n_in,
                              void* d_out, int out_size, void* d_ws, size_t ws_size,
                              hipStream_t stream) {
    const float* x    = (const float*)d_in[0];
    const float* wgt  = (const float*)d_in[1];
    const float* bias = (const float*)d_in[2];
    float* out = (float*)d_out;

    int OUT = in_sizes[2];
    int IN  = in_sizes[1] / OUT;
    int T   = in_sizes[0] / IN;

    char* p = (char*)d_ws;
    int8_t* xq     = (int8_t*)p;   p += (size_t)T * IN;
    int8_t* wq     = (int8_t*)p;   p += (size_t)OUT * IN;
    ushort_t* xoc2 = (ushort_t*)p; p += (size_t)T * KEXT * 2;
    ushort_t* woc2 = (ushort_t*)p; p += (size_t)OUT * KEXT * 2;
    float* wscale  = (float*)p;    p += (size_t)OUT * 4;
    float* xscale  = (float*)p;    p += (size_t)T * 4;
    float* colmax  = (float*)p;    p += (size_t)IN * 4;
    int*   nout    = (int*)p;      p += 256;
    int*   oidx    = (int*)p;      p += MAXOUT * 4;
    float* partial = (float*)p;    p += (size_t)NSLAB * IN * 4;

    int n4 = IN / 4;
    int gx = (n4 + 255) / 256;
    colmax_part_kernel<<<dim3(gx, NSLAB), dim3(256), 0, stream>>>(
        x, partial, nout, n4, T / NSLAB);

    colmax_reduce_kernel<<<dim3(IN / 64), dim3(256), 0, stream>>>(
        partial, colmax, nout, oidx, IN);

    int TOTAL = T + OUT;
    int niter = IN / 256;
    bool ok = (IN % 256 == 0) && (niter == 4 || niter == 8 || niter == 16);
    if (ok) {
        int blocks = (TOTAL + 3) / 4;
        switch (niter) {
        case 4:
            quant_kernel<4><<<dim3(blocks), dim3(256), 0, stream>>>(
                x, wgt, colmax, oidx, nout, xq, wq, xscale, wscale, xoc2, woc2, IN, T, TOTAL);
            break;
        case 8:
            quant_kernel<8><<<dim3(blocks), dim3(256), 0, stream>>>(
                x, wgt, colmax, oidx, nout, xq, wq, xscale, wscale, xoc2, woc2, IN, T, TOTAL);
            break;
        default:
            quant_kernel<16><<<dim3(blocks), dim3(256), 0, stream>>>(
                x, wgt, colmax, oidx, nout, xq, wq, xscale, wscale, xoc2, woc2, IN, T, TOTAL);
            break;
        }
    } else {
        quant_generic_kernel<<<dim3(TOTAL), dim3(256), 0, stream>>>(
            x, wgt, colmax, oidx, nout, xq, wq, xscale, wscale, xoc2, woc2, IN, T);
    }

    gemm_kernel<<<dim3(OUT / BN, T / BM), dim3(256), 0, stream>>>(
        xq, wq, xscale, wscale, bias, xoc2, woc2, out, T, IN, OUT);
}